// Round 1
// baseline (851.910 us; speedup 1.0000x reference)
//
#include <hip/hip_runtime.h>

// ---------------------------------------------------------------------------
// GraphConv (DGL norm='both') + residual linear:
//   out = (D_dst^-1/2 * A^T * (D_src^-1/2 * x)) @ W + x @ Wr + (b + br)
// Baseline: atomic-scatter SpMM, LDS-staged dense epilogue.
// ---------------------------------------------------------------------------

__global__ void deg_kernel(const int* __restrict__ src, const int* __restrict__ dst,
                           float* __restrict__ deg_src, float* __restrict__ deg_dst, int e) {
    int i = blockIdx.x * blockDim.x + threadIdx.x;
    if (i < e) {
        atomicAdd(&deg_src[src[i]], 1.0f);
        atomicAdd(&deg_dst[dst[i]], 1.0f);
    }
}

__global__ void norm_kernel(float* __restrict__ deg_src, float* __restrict__ deg_dst, int n) {
    int i = blockIdx.x * blockDim.x + threadIdx.x;
    if (i < n) {
        deg_src[i] = rsqrtf(fmaxf(deg_src[i], 1.0f));
        deg_dst[i] = rsqrtf(fmaxf(deg_dst[i], 1.0f));
    }
}

// One thread per (edge, quad-of-4-features): coalesced float4 gather + 4 atomics.
__global__ void spmm_kernel(const float4* __restrict__ x4, const int* __restrict__ src,
                            const int* __restrict__ dst, const float* __restrict__ ns,
                            float* __restrict__ agg, int e) {
    long tid = (long)blockIdx.x * blockDim.x + threadIdx.x;
    if (tid >= (long)e * 16) return;
    int eid = (int)(tid >> 4);
    int q   = (int)(tid & 15);
    int s = src[eid];
    int d = dst[eid];
    float w = ns[s];
    float4 v = x4[(long)s * 16 + q];
    float* o = agg + (long)d * 64 + q * 4;
    atomicAdd(o + 0, v.x * w);
    atomicAdd(o + 1, v.y * w);
    atomicAdd(o + 2, v.z * w);
    atomicAdd(o + 3, v.w * w);
}

// out[row][j] = (b+br)[j] + sum_k (agg[row][k]*nd[row]) * W[k][j] + x[row][k] * Wr[k][j]
// One wave per row (lane j = output feature), weights staged in LDS.
__global__ __launch_bounds__(256) void out_kernel(
    const float* __restrict__ x, const float* __restrict__ agg,
    const float* __restrict__ nd,
    const float* __restrict__ W, const float* __restrict__ b,
    const float* __restrict__ Wr, const float* __restrict__ br,
    float* __restrict__ out, int n) {
    __shared__ float sW[4096];
    __shared__ float sWr[4096];
    for (int i = threadIdx.x; i < 4096; i += 256) {
        sW[i]  = W[i];
        sWr[i] = Wr[i];
    }
    __syncthreads();
    int lane = threadIdx.x & 63;
    int wid    = (blockIdx.x * blockDim.x + threadIdx.x) >> 6;
    int nwaves = (gridDim.x * blockDim.x) >> 6;
    float bias = b[lane] + br[lane];
    for (int row = wid; row < n; row += nwaves) {
        float nrm   = nd[row];
        float a_own = agg[(long)row * 64 + lane] * nrm;
        float x_own = x[(long)row * 64 + lane];
        float acc = bias;
        #pragma unroll
        for (int k = 0; k < 64; ++k) {
            float av = __shfl(a_own, k);
            float xv = __shfl(x_own, k);
            acc += av * sW[k * 64 + lane] + xv * sWr[k * 64 + lane];
        }
        out[(long)row * 64 + lane] = acc;
    }
}

extern "C" void kernel_launch(void* const* d_in, const int* in_sizes, int n_in,
                              void* d_out, int out_size, void* d_ws, size_t ws_size,
                              hipStream_t stream) {
    const float* x   = (const float*)d_in[0];
    const int*   src = (const int*)d_in[1];
    const int*   dst = (const int*)d_in[2];
    const float* W   = (const float*)d_in[3];
    const float* b   = (const float*)d_in[4];
    const float* Wr  = (const float*)d_in[5];
    const float* br  = (const float*)d_in[6];
    float* out = (float*)d_out;

    const int n = in_sizes[0] / 64;   // 50000
    const int e = in_sizes[1];        // 800000

    float* ws   = (float*)d_ws;
    float* agg  = ws;                       // n*64
    float* nsrc = ws + (size_t)n * 64;      // n  (degree then rsqrt-norm in place)
    float* ndst = nsrc + n;                 // n

    hipMemsetAsync(ws, 0, (size_t)(n * 64 + 2 * n) * sizeof(float), stream);

    deg_kernel<<<(e + 255) / 256, 256, 0, stream>>>(src, dst, nsrc, ndst, e);
    norm_kernel<<<(n + 255) / 256, 256, 0, stream>>>(nsrc, ndst, n);

    long spmm_threads = (long)e * 16;
    spmm_kernel<<<(int)((spmm_threads + 255) / 256), 256, 0, stream>>>(
        (const float4*)x, src, dst, nsrc, agg, e);

    out_kernel<<<512, 256, 0, stream>>>(x, agg, ndst, W, b, Wr, br, out, n);
}

// Round 2
// 288.491 us; speedup vs baseline: 2.9530x; 2.9530x over previous
//
#include <hip/hip_runtime.h>

// ---------------------------------------------------------------------------
// GraphConv (DGL norm='both') + residual linear:
//   out = (D_dst^-1/2 * A^T * (D_src^-1/2 * x)) @ W + x @ Wr + (b + br)
// Round 2: build CSR (by dst) on device, then gather-reduce per node (zero
// feature atomics) fused with the dense epilogue.
// ---------------------------------------------------------------------------

__global__ void hist_kernel(const int* __restrict__ src, const int* __restrict__ dst,
                            int* __restrict__ cs, int* __restrict__ cd, int e) {
    int i = blockIdx.x * blockDim.x + threadIdx.x;
    if (i < e) {
        atomicAdd(&cs[src[i]], 1);
        atomicAdd(&cd[dst[i]], 1);
    }
}

__global__ void norm_kernel(const int* __restrict__ cs, const int* __restrict__ cd,
                            float* __restrict__ ns, float* __restrict__ nd, int n) {
    int i = blockIdx.x * blockDim.x + threadIdx.x;
    if (i < n) {
        ns[i] = rsqrtf((float)max(cs[i], 1));
        nd[i] = rsqrtf((float)max(cd[i], 1));
    }
}

// Scan phase A: per-block (256-wide) partial sums of cd.
__global__ void partial_kernel(const int* __restrict__ cnt, int* __restrict__ part, int n) {
    __shared__ int sm[256];
    int i = blockIdx.x * 256 + threadIdx.x;
    sm[threadIdx.x] = (i < n) ? cnt[i] : 0;
    __syncthreads();
    for (int s = 128; s > 0; s >>= 1) {
        if (threadIdx.x < s) sm[threadIdx.x] += sm[threadIdx.x + s];
        __syncthreads();
    }
    if (threadIdx.x == 0) part[blockIdx.x] = sm[0];
}

// Scan phase B: single-block exclusive scan of the partials (nb <= 256).
__global__ void scan_part_kernel(int* __restrict__ part, int nb) {
    __shared__ int sm[256];
    int t = threadIdx.x;
    int v = (t < nb) ? part[t] : 0;
    sm[t] = v;
    __syncthreads();
    for (int d = 1; d < 256; d <<= 1) {
        int add = (t >= d) ? sm[t - d] : 0;
        __syncthreads();
        sm[t] += add;
        __syncthreads();
    }
    if (t < nb) part[t] = sm[t] - v;   // exclusive
}

// Scan phase C: local exclusive scan + block offset -> row_off and cursor.
__global__ void scan_final_kernel(const int* __restrict__ cnt, const int* __restrict__ part,
                                  int* __restrict__ off, int* __restrict__ cursor,
                                  int n, int e) {
    __shared__ int sm[256];
    int t = threadIdx.x;
    int i = blockIdx.x * 256 + t;
    int v = (i < n) ? cnt[i] : 0;
    sm[t] = v;
    __syncthreads();
    for (int d = 1; d < 256; d <<= 1) {
        int add = (t >= d) ? sm[t - d] : 0;
        __syncthreads();
        sm[t] += add;
        __syncthreads();
    }
    int excl = sm[t] - v + part[blockIdx.x];
    if (i < n) {
        off[i]    = excl;
        cursor[i] = excl;
    }
    if (i == n - 1) off[n] = e;
}

// Scatter edge sources into CSR col array (order within a row is arbitrary).
__global__ void scatter_kernel(const int* __restrict__ src, const int* __restrict__ dst,
                               int* __restrict__ cursor, int* __restrict__ col, int e) {
    int i = blockIdx.x * blockDim.x + threadIdx.x;
    if (i < e) {
        int p = atomicAdd(&cursor[dst[i]], 1);
        col[p] = src[i];
    }
}

// One wave per node (lane = feature). Gather-scale-reduce incoming neighbors,
// then fused dense epilogue: out = (acc*nd) @ W + x @ Wr + (b+br).
__global__ __launch_bounds__(256) void gather_out_kernel(
    const float* __restrict__ x, const int* __restrict__ col,
    const int* __restrict__ row_off,
    const float* __restrict__ ns, const float* __restrict__ nd,
    const float* __restrict__ W, const float* __restrict__ b,
    const float* __restrict__ Wr, const float* __restrict__ br,
    float* __restrict__ out, int n) {
    __shared__ float sW[4096];
    __shared__ float sWr[4096];
    for (int i = threadIdx.x; i < 4096; i += 256) {
        sW[i]  = W[i];
        sWr[i] = Wr[i];
    }
    __syncthreads();

    int lane = threadIdx.x & 63;
    int node = (blockIdx.x * 256 + threadIdx.x) >> 6;
    if (node >= n) return;
    node = __builtin_amdgcn_readfirstlane(node);   // wave-uniform -> scalar loads

    int beg = row_off[node];
    int end = row_off[node + 1];

    float acc = 0.0f;
    for (int j = beg; j < end; ++j) {
        int s = col[j];                       // wave-uniform broadcast load
        acc += ns[s] * x[(long)s * 64 + lane];  // coalesced 256B row gather
    }

    float a_own = acc * nd[node];
    float x_own = x[(long)node * 64 + lane];
    float r = b[lane] + br[lane];
    #pragma unroll
    for (int k = 0; k < 64; ++k) {
        float av = __shfl(a_own, k);
        float xv = __shfl(x_own, k);
        r += av * sW[k * 64 + lane] + xv * sWr[k * 64 + lane];
    }
    out[(long)node * 64 + lane] = r;
}

extern "C" void kernel_launch(void* const* d_in, const int* in_sizes, int n_in,
                              void* d_out, int out_size, void* d_ws, size_t ws_size,
                              hipStream_t stream) {
    const float* x   = (const float*)d_in[0];
    const int*   src = (const int*)d_in[1];
    const int*   dst = (const int*)d_in[2];
    const float* W   = (const float*)d_in[3];
    const float* b   = (const float*)d_in[4];
    const float* Wr  = (const float*)d_in[5];
    const float* br  = (const float*)d_in[6];
    float* out = (float*)d_out;

    const int n = in_sizes[0] / 64;   // 50000
    const int e = in_sizes[1];        // 800000
    const int nblk = (n + 255) / 256; // 196 partial blocks (<= 256)

    // Workspace layout (ints/floats are both 4B):
    char* p = (char*)d_ws;
    int*   cs     = (int*)p;            p += (size_t)n * 4;
    int*   cd     = (int*)p;            p += (size_t)n * 4;
    float* ns     = (float*)p;          p += (size_t)n * 4;
    float* nd     = (float*)p;          p += (size_t)n * 4;
    int*   roff   = (int*)p;            p += (size_t)(n + 1) * 4;
    int*   cursor = (int*)p;            p += (size_t)n * 4;
    int*   part   = (int*)p;            p += 256 * 4;
    int*   col    = (int*)p;            // e ints

    // Zero only the histogram counters (everything else fully overwritten).
    hipMemsetAsync(cs, 0, (size_t)n * 2 * sizeof(int), stream);

    hist_kernel<<<(e + 255) / 256, 256, 0, stream>>>(src, dst, cs, cd, e);
    norm_kernel<<<(n + 255) / 256, 256, 0, stream>>>(cs, cd, ns, nd, n);

    partial_kernel<<<nblk, 256, 0, stream>>>(cd, part, n);
    scan_part_kernel<<<1, 256, 0, stream>>>(part, nblk);
    scan_final_kernel<<<nblk, 256, 0, stream>>>(cd, part, roff, cursor, n, e);

    scatter_kernel<<<(e + 255) / 256, 256, 0, stream>>>(src, dst, cursor, col, e);

    gather_out_kernel<<<(n * 64 + 255) / 256, 256, 0, stream>>>(
        x, col, roff, ns, nd, W, b, Wr, br, out, n);
}